// Round 13
// baseline (90.590 us; speedup 1.0000x reference)
//
#include <hip/hip_runtime.h>
#include <hip/hip_bf16.h>

typedef __attribute__((ext_vector_type(8))) short bf16x8;
typedef __attribute__((ext_vector_type(4))) float f32x4;

#define BATCH 2
#define T_SEQ 2048
#define C_EMB 1024
#define NH 16
#define HS 64

// async 16B global -> LDS (wave-uniform LDS base, + lane*16 implicit)
__device__ __forceinline__ void gld_lds16(const __hip_bfloat16* g, void* l) {
    __builtin_amdgcn_global_load_lds((const __attribute__((address_space(1))) uint32_t*)g,
                                     (__attribute__((address_space(3))) uint32_t*)l, 16, 0, 0);
}

// ---------------- fp32 -> bf16 convert (both arrays, one launch) ----------------
__global__ void cvt_f32_bf16(const float4* __restrict__ s0, ushort4* __restrict__ d0, int n40,
                             const float4* __restrict__ s1, ushort4* __restrict__ d1, int n41) {
    int i = blockIdx.x * blockDim.x + threadIdx.x;
    const float4* s; ushort4* d; int j;
    if (i < n40)            { s = s0; d = d0; j = i; }
    else if (i < n40 + n41) { s = s1; d = d1; j = i - n40; }
    else return;
    float4 v = s[j];
    ushort4 o;
    __hip_bfloat16 h;
    h = __float2bfloat16(v.x); o.x = *(ushort*)&h;
    h = __float2bfloat16(v.y); o.y = *(ushort*)&h;
    h = __float2bfloat16(v.z); o.z = *(ushort*)&h;
    h = __float2bfloat16(v.w); o.w = *(ushort*)&h;
    d[j] = o;
}

// ---------------- QKV projection GEMM (unchanged from R7-R12) ----------------
#define NT_K 16   // 1024/64

__launch_bounds__(512, 2)
__global__ void qkv_gemm(const __hip_bfloat16* __restrict__ xb,   // [4096][1024]
                         const __hip_bfloat16* __restrict__ wb,   // [3072][1024]
                         const float* __restrict__ bias,          // [3072]
                         __hip_bfloat16* __restrict__ qo,         // [BH][T][64] (pre-scaled)
                         __hip_bfloat16* __restrict__ ko,         // [BH][T][64]
                         __hip_bfloat16* __restrict__ vto)        // [BH][64][T]
{
    __shared__ __align__(16) char smem[131072];
    __hip_bfloat16* ASB = (__hip_bfloat16*)smem;              // As: [2][2][256*32]
    __hip_bfloat16* BSB = (__hip_bfloat16*)(smem + 65536);    // Bs: [2][2][256*32]
    const int K = C_EMB;
    const int nTn = (3 * C_EMB) / 256;   // 12
    int bid = blockIdx.x;
    int wgid = (bid & 7) * 24 + (bid >> 3);   // 192 blocks, bijective XCD swizzle
    int bm = wgid / nTn, bn = wgid % nTn;
    int m0 = bm * 256, n0 = bn * 256;
    int tid  = threadIdx.x;
    int lane = tid & 63, w = tid >> 6;
    int wr = w >> 2, wc = w & 3;
    int c = lane & 15, g = lane >> 4;
    int sr = lane >> 2;                          // row offset 0..15
    int sj = (lane & 3) ^ ((sr >> 1) & 3);       // logical 16B chunk to fetch
    int rchnk = (g ^ ((c >> 1) & 3)) << 4;       // read-side physical chunk (bytes)

#define STAGE_A(kt, kh, buf) \
    { _Pragma("unroll") for (int i_ = 0; i_ < 2; ++i_) { \
        int r0_ = w * 32 + i_ * 16; \
        gld_lds16(&xb[(size_t)(m0 + r0_ + sr) * K + (kt) * 64 + (kh) * 32 + sj * 8], \
                  &ASB[((buf) * 2 + (kh)) * 8192 + r0_ * 32]); } }
#define STAGE_B(kt, kh, buf) \
    { _Pragma("unroll") for (int i_ = 0; i_ < 2; ++i_) { \
        int r0_ = w * 32 + i_ * 16; \
        gld_lds16(&wb[(size_t)(n0 + r0_ + sr) * K + (kt) * 64 + (kh) * 32 + sj * 8], \
                  &BSB[((buf) * 2 + (kh)) * 8192 + r0_ * 32]); } }

    f32x4 acc[8][4];
#pragma unroll
    for (int mi = 0; mi < 8; ++mi)
#pragma unroll
        for (int ni = 0; ni < 4; ++ni)
            acc[mi][ni] = (f32x4){0.f, 0.f, 0.f, 0.f};

    STAGE_A(0, 0, 0); STAGE_B(0, 0, 0);
    STAGE_A(0, 1, 0); STAGE_B(0, 1, 0);
    STAGE_A(1, 0, 1); STAGE_B(1, 0, 1);
    asm volatile("s_waitcnt vmcnt(4)" ::: "memory");
    __builtin_amdgcn_s_barrier();

    for (int t = 0; t < NT_K; ++t) {
        int buf = t & 1;
#pragma unroll
        for (int ks = 0; ks < 2; ++ks) {
            const __hip_bfloat16* AL = &ASB[(buf * 2 + ks) * 8192];
            const __hip_bfloat16* BL = &BSB[(buf * 2 + ks) * 8192];
            bf16x8 af[8], bfr[4];
#pragma unroll
            for (int mi = 0; mi < 8; ++mi)
                af[mi] = *(const bf16x8*)((const char*)AL + (wr * 128 + mi * 16 + c) * 64 + rchnk);
#pragma unroll
            for (int ni = 0; ni < 4; ++ni)
                bfr[ni] = *(const bf16x8*)((const char*)BL + (wc * 64 + ni * 16 + c) * 64 + rchnk);
            if (ks == 0) {
                if (t + 1 < NT_K) { STAGE_A(t + 1, 1, buf ^ 1); STAGE_B(t + 1, 1, buf ^ 1); }
            } else {
                if (t + 2 < NT_K) { STAGE_A(t + 2, 0, buf); STAGE_B(t + 2, 0, buf); }
            }
            __builtin_amdgcn_s_barrier();
            asm volatile("s_waitcnt lgkmcnt(0)" ::: "memory");
            __builtin_amdgcn_s_setprio(1);
#pragma unroll
            for (int mi = 0; mi < 8; ++mi)
#pragma unroll
                for (int ni = 0; ni < 4; ++ni)
                    acc[mi][ni] = __builtin_amdgcn_mfma_f32_16x16x32_bf16(af[mi], bfr[ni], acc[mi][ni], 0, 0, 0);
            __builtin_amdgcn_s_setprio(0);
            if (ks == 1) {
                if (t + 2 < NT_K) asm volatile("s_waitcnt vmcnt(4)" ::: "memory");
                else              asm volatile("s_waitcnt vmcnt(0)" ::: "memory");
            }
            __builtin_amdgcn_s_barrier();
        }
    }
#undef STAGE_A
#undef STAGE_B

    const float QSCALE = 0.125f * 1.44269504088896340736f;  // HS^-0.5 * log2(e)
    if (bn < 8) {
        const bool isQ = (bn < 4);
        __hip_bfloat16* dst = isQ ? qo : ko;
        float scale = isQ ? QSCALE : 1.0f;
        int h = (bn * 4 + wc) & (NH - 1);
        int b = m0 >> 11;
        size_t bhb = (size_t)(b * NH + h) * T_SEQ;
#pragma unroll
        for (int ni = 0; ni < 4; ++ni) {
            int d = ni * 16 + c;
            float bv = bias[n0 + wc * 64 + d];
#pragma unroll
            for (int mi = 0; mi < 8; ++mi) {
#pragma unroll
                for (int r = 0; r < 4; ++r) {
                    int tt = (m0 & (T_SEQ - 1)) + wr * 128 + mi * 16 + g * 4 + r;
                    float v = (acc[mi][ni][r] + bv) * scale;
                    dst[(bhb + tt) * HS + d] = __float2bfloat16(v);
                }
            }
        }
    } else {
        // V block: per-wave LDS transpose -> coalesced 16B vto stores
        __syncthreads();
        char* tb = smem + w * 16384;
        int h = (bn - 8) * 4 + wc;
#pragma unroll
        for (int ni = 0; ni < 4; ++ni) {
            int d = ni * 16 + c;
            float bv = bias[n0 + wc * 64 + d];
#pragma unroll
            for (int mi = 0; mi < 8; ++mi) {
#pragma unroll
                for (int r = 0; r < 4; ++r) {
                    int m = mi * 16 + g * 4 + r;
                    __hip_bfloat16 hv = __float2bfloat16(acc[mi][ni][r] + bv);
                    *(ushort*)(tb + d * 256 + (((m >> 3) ^ c) << 4) + (m & 7) * 2) = *(ushort*)&hv;
                }
            }
        }
        int b = m0 >> 11;
        int t0 = (m0 & (T_SEQ - 1)) + wr * 128;
        size_t bh = (size_t)(b * NH + h);
        int c2 = lane & 15, g2 = lane >> 4;
#pragma unroll
        for (int it = 0; it < 16; ++it) {
            int d = it * 4 + g2;
            bf16x8 vv = *(bf16x8*)(tb + d * 256 + ((c2 ^ (d & 15)) << 4));
            *(bf16x8*)(&vto[(bh * HS + d) * T_SEQ + t0 + c2 * 8]) = vv;
        }
    }
}

// ---------------- causal flash attention with KV-split ----------------
// No-max softmax makes partials ADDITIVE: O = sum p*v, l = sum p over any KV
// partition. qt<=15: one block, writes normalized out. qt>=16: two blocks —
// chunk0 (KV [0,h)) writes unnormalized fp32 O -> ws_part + l0; chunk1
// (KV [h,qt+1), has diagonal) writes unnormalized O -> out + l1. attn_reduce
// combines. Longest serial chain: 32 -> 16 steps. 1536 blocks, 4 blocks/CU.
__launch_bounds__(256, 4)
__global__ void attn_fwd(const __hip_bfloat16* __restrict__ qb,   // [BH][T][64], *0.125*log2e
                         const __hip_bfloat16* __restrict__ kb,   // [BH][T][64]
                         const __hip_bfloat16* __restrict__ vtb,  // [BH][64][T]
                         float* __restrict__ out,                 // [B][T][C]
                         float* __restrict__ ws_part,             // [512][64][64]
                         float* __restrict__ ws_l0,               // [512][64]
                         float* __restrict__ ws_l1)               // [512][64]
{
    __shared__ __align__(16) char smem[40960];

    int idx = blockIdx.x;
    int bh = idx & 31;
    int j  = idx >> 5;                   // 0..47, longest work first
    int qt, c0, c1, mode;                // mode: 0=direct 1=chunk0 2=chunk1
    if (j < 32) {
        qt = 31 - (j >> 1);
        int hsp = (qt + 2) >> 1;         // ceil((qt+1)/2)
        if ((j & 1) == 0) { c0 = 0; c1 = hsp; mode = 1; }
        else             { c0 = hsp; c1 = qt + 1; mode = 2; }
    } else {
        qt = 47 - j;                     // 15..0
        c0 = 0; c1 = qt + 1; mode = 0;
    }
    int w  = threadIdx.x >> 6;           // wave 0..3
    int lane = threadIdx.x & 63;
    int c = lane & 15, g = lane >> 4;
    char* p_strip = smem + 32768 + w * 2048;

    const __hip_bfloat16* Qp = qb  + (size_t)bh * T_SEQ * HS;
    const __hip_bfloat16* Kp = kb  + (size_t)bh * T_SEQ * HS;
    const __hip_bfloat16* Vp = vtb + (size_t)bh * HS * T_SEQ;
    int b = bh >> 4, h = bh & (NH - 1);

    int srow = lane >> 3;
    int scol = ((lane & 7) ^ srow) << 3;     // pre-swizzled source col (elems)
    int swz  = (c & 7) << 4;                 // K/V read-side XOR (bytes)
    int krow0 = w * 16 + srow;
    int krow1 = w * 16 + 8 + srow;
    int qw = qt * 64 + w * 16;

    bf16x8 qf[2];
    qf[0] = *(const bf16x8*)(&Qp[(size_t)(qw + c) * HS + g * 8]);
    qf[1] = *(const bf16x8*)(&Qp[(size_t)(qw + c) * HS + 32 + g * 8]);

    f32x4 oacc[4];
#pragma unroll
    for (int i = 0; i < 4; ++i) oacc[i] = (f32x4){0.f, 0.f, 0.f, 0.f};
    float lrow = 0.f;

#define ATT_STAGE(t_, buf_) { \
    int k0_ = (t_) * 64; \
    char* kb_ = smem + (buf_) * 8192; \
    char* vb_ = smem + 16384 + (buf_) * 8192; \
    gld_lds16(&Kp[(size_t)(k0_ + krow0) * HS + scol],  kb_ + (w * 16) * 128); \
    gld_lds16(&Kp[(size_t)(k0_ + krow1) * HS + scol],  kb_ + (w * 16 + 8) * 128); \
    gld_lds16(&Vp[(size_t)krow0 * T_SEQ + k0_ + scol], vb_ + (w * 16) * 128); \
    gld_lds16(&Vp[(size_t)krow1 * T_SEQ + k0_ + scol], vb_ + (w * 16 + 8) * 128); }

    ATT_STAGE(c0, 0);

    for (int tix = c0; tix < c1; ++tix) {
        int cur = (tix - c0) & 1;
        asm volatile("s_waitcnt vmcnt(0)" ::: "memory");
        __builtin_amdgcn_s_barrier();
        if (tix + 1 < c1) ATT_STAGE(tix + 1, cur ^ 1);

        bool diag = (tix == qt);
        const char* KL = smem + cur * 8192;
        const char* VL = smem + 16384 + cur * 8192;

        f32x4 sacc[4];
#pragma unroll
        for (int i = 0; i < 4; ++i) sacc[i] = (f32x4){0.f, 0.f, 0.f, 0.f};
        __builtin_amdgcn_s_setprio(1);
#pragma unroll
        for (int ks = 0; ks < 2; ++ks)
#pragma unroll
            for (int kc = 0; kc < 4; ++kc)
                if (!diag || kc <= w) {
                    int rr = kc * 16 + c;
                    int colB = (ks * 64 + g * 16) ^ swz;
                    bf16x8 kf = *(const bf16x8*)(KL + rr * 128 + colB);
                    sacc[kc] = __builtin_amdgcn_mfma_f32_16x16x32_bf16(kf, qf[ks], sacc[kc], 0, 0, 0);
                }
        __builtin_amdgcn_s_setprio(0);

#pragma unroll
        for (int kc = 0; kc < 4; ++kc) {
            float p0, p1, p2, p3;
            if (!diag) {
                p0 = __builtin_amdgcn_exp2f(sacc[kc][0]);
                p1 = __builtin_amdgcn_exp2f(sacc[kc][1]);
                p2 = __builtin_amdgcn_exp2f(sacc[kc][2]);
                p3 = __builtin_amdgcn_exp2f(sacc[kc][3]);
            } else {
                int kbase = kc * 16 + g * 4;
                int lim = w * 16 + c;
                p0 = (kc <= w && kbase + 0 <= lim) ? __builtin_amdgcn_exp2f(sacc[kc][0]) : 0.f;
                p1 = (kc <= w && kbase + 1 <= lim) ? __builtin_amdgcn_exp2f(sacc[kc][1]) : 0.f;
                p2 = (kc <= w && kbase + 2 <= lim) ? __builtin_amdgcn_exp2f(sacc[kc][2]) : 0.f;
                p3 = (kc <= w && kbase + 3 <= lim) ? __builtin_amdgcn_exp2f(sacc[kc][3]) : 0.f;
            }
            lrow += (p0 + p1) + (p2 + p3);
            unsigned lo = ((__builtin_bit_cast(unsigned, p0) + 0x8000u) >> 16) |
                          ((__builtin_bit_cast(unsigned, p1) + 0x8000u) & 0xffff0000u);
            unsigned hi = ((__builtin_bit_cast(unsigned, p2) + 0x8000u) >> 16) |
                          ((__builtin_bit_cast(unsigned, p3) + 0x8000u) & 0xffff0000u);
            int gran = ((kc * 2 + (g >> 1)) ^ (c & 7)) << 4;
            *(uint2*)(p_strip + c * 128 + gran + ((g & 1) << 3)) = make_uint2(lo, hi);
        }

        int ksm = diag ? ((w >= 2) ? 2 : 1) : 2;
        __builtin_amdgcn_s_setprio(1);
#pragma unroll
        for (int ks = 0; ks < 2; ++ks) {
            if (ks >= ksm) break;
            int pgran = ((ks * 4 + g) ^ (c & 7)) << 4;
            bf16x8 pf = *(bf16x8*)(p_strip + c * 128 + pgran);
#pragma unroll
            for (int d16 = 0; d16 < 4; ++d16) {
                int dr = d16 * 16 + c;
                int colB = (ks * 64 + g * 16) ^ swz;
                bf16x8 vf = *(const bf16x8*)(VL + dr * 128 + colB);
                oacc[d16] = __builtin_amdgcn_mfma_f32_16x16x32_bf16(vf, pf, oacc[d16], 0, 0, 0);
            }
        }
        __builtin_amdgcn_s_setprio(0);
    }

    // ---- finalize ----
    float v = lrow;
    v += __shfl_xor(v, 16, 64);
    v += __shfl_xor(v, 32, 64);   // v uniform over g for fixed c

    int lr = w * 16 + c;          // local row 0..63
    if (mode == 0) {
        float linv = 1.0f / v;
        float* orow = &out[((size_t)(b * T_SEQ + qw + c)) * C_EMB + h * HS + g * 4];
#pragma unroll
        for (int d16 = 0; d16 < 4; ++d16) {
            float4 st;
            st.x = oacc[d16][0] * linv;
            st.y = oacc[d16][1] * linv;
            st.z = oacc[d16][2] * linv;
            st.w = oacc[d16][3] * linv;
            *(float4*)(&orow[d16 * 16]) = st;
        }
    } else {
        int pid = (qt - 16) * 32 + bh;
        if (mode == 1) {
            float* pO = ws_part + (size_t)pid * 4096;
#pragma unroll
            for (int d16 = 0; d16 < 4; ++d16) {
                float4 st;
                st.x = oacc[d16][0]; st.y = oacc[d16][1];
                st.z = oacc[d16][2]; st.w = oacc[d16][3];
                *(float4*)(&pO[lr * 64 + d16 * 16 + g * 4]) = st;
            }
            if (g == 0) ws_l0[pid * 64 + lr] = v;
        } else {
            float* orow = &out[((size_t)(b * T_SEQ + qw + c)) * C_EMB + h * HS + g * 4];
#pragma unroll
            for (int d16 = 0; d16 < 4; ++d16) {
                float4 st;
                st.x = oacc[d16][0]; st.y = oacc[d16][1];
                st.z = oacc[d16][2]; st.w = oacc[d16][3];
                *(float4*)(&orow[d16 * 16]) = st;
            }
            if (g == 0) ws_l1[pid * 64 + lr] = v;
        }
    }
#undef ATT_STAGE
}

// ---------------- combine KV-split partials: out = (out + part) / (l0+l1) ----------------
__global__ void attn_reduce(float* __restrict__ out, const float* __restrict__ part,
                            const float* __restrict__ l0, const float* __restrict__ l1) {
    int idx = blockIdx.x * 256 + threadIdx.x;       // 524288 threads
    int pid = idx >> 10;                            // 0..511
    int rem = idx & 1023;
    int lr = rem >> 4, f4 = (rem & 15) * 4;
    int qt = 16 + (pid >> 5), bh = pid & 31;
    int b = bh >> 4, h = bh & (NH - 1);
    float linv = 1.0f / (l0[pid * 64 + lr] + l1[pid * 64 + lr]);
    float* dst = &out[((size_t)(b * T_SEQ + qt * 64 + lr)) * C_EMB + h * HS + f4];
    float4 a = *(float4*)dst;
    float4 p = *(const float4*)(&part[(size_t)pid * 4096 + lr * 64 + f4]);
    a.x = (a.x + p.x) * linv;
    a.y = (a.y + p.y) * linv;
    a.z = (a.z + p.z) * linv;
    a.w = (a.w + p.w) * linv;
    *(float4*)dst = a;
}

// ---------------- launch ----------------
extern "C" void kernel_launch(void* const* d_in, const int* in_sizes, int n_in,
                              void* d_out, int out_size, void* d_ws, size_t ws_size,
                              hipStream_t stream) {
    const float* x    = (const float*)d_in[0];   // [2][2048][1024]
    const float* W    = (const float*)d_in[1];   // [3072][1024]
    const float* bias = (const float*)d_in[2];   // [3072]
    float* out = (float*)d_out;

    char* ws = (char*)d_ws;
    __hip_bfloat16* xb  = (__hip_bfloat16*)(ws);                      // 8 MB (dead after gemm)
    __hip_bfloat16* wb  = (__hip_bfloat16*)(ws + (8u  << 20));        // 6 MB (dead after gemm)
    __hip_bfloat16* qo  = (__hip_bfloat16*)(ws + (14u << 20));        // 8 MB
    __hip_bfloat16* ko  = (__hip_bfloat16*)(ws + (22u << 20));        // 8 MB
    __hip_bfloat16* vto = (__hip_bfloat16*)(ws + (30u << 20));        // 8 MB
    // KV-split partials overlay the xb/wb region (free once gemm is done):
    float* ws_part = (float*)(ws);                                    // 512*64*64*4 = 8 MB
    float* ws_l0   = (float*)(ws + (8u << 20));                       // 128 KB
    float* ws_l1   = (float*)(ws + (8u << 20) + (1u << 17));          // 128 KB

    int n4x = BATCH * T_SEQ * C_EMB / 4;      // 1048576
    int n4w = 3 * C_EMB * C_EMB / 4;          // 786432
    int n4  = n4x + n4w;
    cvt_f32_bf16<<<(n4 + 255) / 256, 256, 0, stream>>>(
        (const float4*)x, (ushort4*)xb, n4x,
        (const float4*)W, (ushort4*)wb, n4w);

    int gemm_grid = (BATCH * T_SEQ / 256) * (3 * C_EMB / 256);  // 16*12 = 192
    qkv_gemm<<<gemm_grid, 512, 0, stream>>>(xb, wb, bias, qo, ko, vto);

    attn_fwd<<<1536, 256, 0, stream>>>(qo, ko, vto, out, ws_part, ws_l0, ws_l1);
    attn_reduce<<<2048, 256, 0, stream>>>(out, ws_part, ws_l0, ws_l1);
}

// Round 14
// 78.095 us; speedup vs baseline: 1.1600x; 1.1600x over previous
//
#include <hip/hip_runtime.h>
#include <hip/hip_bf16.h>

typedef __attribute__((ext_vector_type(8))) short bf16x8;
typedef __attribute__((ext_vector_type(4))) float f32x4;

#define BATCH 2
#define T_SEQ 2048
#define C_EMB 1024
#define NH 16
#define HS 64

// async 16B global -> LDS (wave-uniform LDS base, + lane*16 implicit)
__device__ __forceinline__ void gld_lds16(const __hip_bfloat16* g, void* l) {
    __builtin_amdgcn_global_load_lds((const __attribute__((address_space(1))) uint32_t*)g,
                                     (__attribute__((address_space(3))) uint32_t*)l, 16, 0, 0);
}

// ---------------- fp32 -> bf16 convert (both arrays, one launch) ----------------
__global__ void cvt_f32_bf16(const float4* __restrict__ s0, ushort4* __restrict__ d0, int n40,
                             const float4* __restrict__ s1, ushort4* __restrict__ d1, int n41) {
    int i = blockIdx.x * blockDim.x + threadIdx.x;
    const float4* s; ushort4* d; int j;
    if (i < n40)            { s = s0; d = d0; j = i; }
    else if (i < n40 + n41) { s = s1; d = d1; j = i - n40; }
    else return;
    float4 v = s[j];
    ushort4 o;
    __hip_bfloat16 h;
    h = __float2bfloat16(v.x); o.x = *(ushort*)&h;
    h = __float2bfloat16(v.y); o.y = *(ushort*)&h;
    h = __float2bfloat16(v.z); o.z = *(ushort*)&h;
    h = __float2bfloat16(v.w); o.w = *(ushort*)&h;
    d[j] = o;
}

// ---------------- QKV projection GEMM: 256x192 tile -> 256 blocks (full fill) ----
// M=4096, N=3072, K=1024. 16x16 = 256 blocks = exactly 1/CU (was 192 -> 64 CUs
// idle). 8 waves (2M x 4N), per-wave 128x48 (8x3 frags). Every 16-col frag is
// section-pure (boundaries at 1024/2048 are 64-aligned, frags 16-aligned).
// LDS: A[2][2][256x32] 64KB + B[2][2][192x32] 48KB = 112KB. B staged by waves
// 0-3 (2 chunks) / 4-7 (1 chunk) -> per-wave vmcnt 4/3. 2-phase counted-vmcnt.
#define NT_K 16   // 1024/64

__launch_bounds__(512, 2)
__global__ void qkv_gemm(const __hip_bfloat16* __restrict__ xb,   // [4096][1024]
                         const __hip_bfloat16* __restrict__ wb,   // [3072][1024]
                         const float* __restrict__ bias,          // [3072]
                         __hip_bfloat16* __restrict__ qo,         // [BH][T][64] (pre-scaled)
                         __hip_bfloat16* __restrict__ ko,         // [BH][T][64]
                         __hip_bfloat16* __restrict__ vto)        // [BH][64][T]
{
    __shared__ __align__(16) char smem[114688];
    __hip_bfloat16* ASB = (__hip_bfloat16*)smem;              // [2][2][256*32] = 64KB
    __hip_bfloat16* BSB = (__hip_bfloat16*)(smem + 65536);    // [2][2][192*32] = 48KB
    const int K = C_EMB;
    const int nTn = (3 * C_EMB) / 192;   // 16
    int bid = blockIdx.x;
    int wgid = (bid & 7) * 32 + (bid >> 3);   // 256 blocks, bijective XCD swizzle
    int bm = wgid / nTn, bn = wgid % nTn;
    int m0 = bm * 256, n0 = bn * 192;
    int tid  = threadIdx.x;
    int lane = tid & 63, w = tid >> 6;
    int wr = w >> 2, wc = w & 3;
    int c = lane & 15, g = lane >> 4;
    int sr = lane >> 2;                          // staging row offset 0..15
    int sj = (lane & 3) ^ ((sr >> 1) & 3);       // logical 16B chunk (pre-swizzle)
    int rchnk = (g ^ ((c >> 1) & 3)) << 4;       // read-side physical chunk (bytes)

#define STAGE_A(kt, kh, buf) \
    { _Pragma("unroll") for (int i_ = 0; i_ < 2; ++i_) { \
        int r0_ = w * 32 + i_ * 16; \
        gld_lds16(&xb[(size_t)(m0 + r0_ + sr) * K + (kt) * 64 + (kh) * 32 + sj * 8], \
                  &ASB[((buf) * 2 + (kh)) * 8192 + r0_ * 32]); } }
#define STAGE_B(kt, kh, buf) \
    { if (w < 4) { \
        gld_lds16(&wb[(size_t)(n0 + w * 32 + sr) * K + (kt) * 64 + (kh) * 32 + sj * 8], \
                  &BSB[((buf) * 2 + (kh)) * 6144 + (w * 32) * 32]); \
        gld_lds16(&wb[(size_t)(n0 + w * 32 + 16 + sr) * K + (kt) * 64 + (kh) * 32 + sj * 8], \
                  &BSB[((buf) * 2 + (kh)) * 6144 + (w * 32 + 16) * 32]); \
      } else { \
        gld_lds16(&wb[(size_t)(n0 + 128 + (w - 4) * 16 + sr) * K + (kt) * 64 + (kh) * 32 + sj * 8], \
                  &BSB[((buf) * 2 + (kh)) * 6144 + (128 + (w - 4) * 16) * 32]); \
      } }

    f32x4 acc[8][3];
#pragma unroll
    for (int mi = 0; mi < 8; ++mi)
#pragma unroll
        for (int ni = 0; ni < 3; ++ni)
            acc[mi][ni] = (f32x4){0.f, 0.f, 0.f, 0.f};

    // prologue: k0(0), k1(0), k0(1); wait first two halves, keep third in flight
    STAGE_A(0, 0, 0); STAGE_B(0, 0, 0);
    STAGE_A(0, 1, 0); STAGE_B(0, 1, 0);
    STAGE_A(1, 0, 1); STAGE_B(1, 0, 1);
    if (w < 4) asm volatile("s_waitcnt vmcnt(4)" ::: "memory");
    else       asm volatile("s_waitcnt vmcnt(3)" ::: "memory");
    __builtin_amdgcn_s_barrier();

    for (int t = 0; t < NT_K; ++t) {
        int buf = t & 1;
#pragma unroll
        for (int ks = 0; ks < 2; ++ks) {
            const __hip_bfloat16* AL = &ASB[(buf * 2 + ks) * 8192];
            const __hip_bfloat16* BL = &BSB[(buf * 2 + ks) * 6144];
            bf16x8 af[8], bfr[3];
#pragma unroll
            for (int mi = 0; mi < 8; ++mi)
                af[mi] = *(const bf16x8*)((const char*)AL + (wr * 128 + mi * 16 + c) * 64 + rchnk);
#pragma unroll
            for (int ni = 0; ni < 3; ++ni)
                bfr[ni] = *(const bf16x8*)((const char*)BL + (wc * 48 + ni * 16 + c) * 64 + rchnk);
            if (ks == 0) {
                if (t + 1 < NT_K) { STAGE_A(t + 1, 1, buf ^ 1); STAGE_B(t + 1, 1, buf ^ 1); }
            } else {
                if (t + 2 < NT_K) { STAGE_A(t + 2, 0, buf); STAGE_B(t + 2, 0, buf); }
            }
            __builtin_amdgcn_s_barrier();
            asm volatile("s_waitcnt lgkmcnt(0)" ::: "memory");
            __builtin_amdgcn_s_setprio(1);
#pragma unroll
            for (int mi = 0; mi < 8; ++mi)
#pragma unroll
                for (int ni = 0; ni < 3; ++ni)
                    acc[mi][ni] = __builtin_amdgcn_mfma_f32_16x16x32_bf16(af[mi], bfr[ni], acc[mi][ni], 0, 0, 0);
            __builtin_amdgcn_s_setprio(0);
            if (ks == 1) {
                if (t + 2 < NT_K) {
                    if (w < 4) asm volatile("s_waitcnt vmcnt(4)" ::: "memory");
                    else       asm volatile("s_waitcnt vmcnt(3)" ::: "memory");
                } else {
                    asm volatile("s_waitcnt vmcnt(0)" ::: "memory");
                }
            }
            __builtin_amdgcn_s_barrier();
        }
    }
#undef STAGE_A
#undef STAGE_B

    // ---- epilogue: per-frag routing (each 16-col frag is section-pure) ----
    const float QSCALE = 0.125f * 1.44269504088896340736f;  // HS^-0.5 * log2(e)
    __syncthreads();                    // reclaim staging LDS for V scratch
    int b = m0 >> 11;
    int t0 = (m0 & (T_SEQ - 1)) + wr * 128;
#pragma unroll
    for (int ni = 0; ni < 3; ++ni) {
        int nb = n0 + wc * 48 + ni * 16;     // frag base column
        int s = nb >> 10;
        int h = (nb >> 6) & (NH - 1);
        float bv = bias[nb + c];
        if (s < 2) {
            __hip_bfloat16* dst = (s == 0) ? qo : ko;
            float scale = (s == 0) ? QSCALE : 1.0f;
            int dd = (nb & 63) + c;
            size_t bhb = (size_t)(b * NH + h) * T_SEQ;
#pragma unroll
            for (int mi = 0; mi < 8; ++mi) {
#pragma unroll
                for (int r = 0; r < 4; ++r) {
                    int tt = t0 + mi * 16 + g * 4 + r;
                    dst[(bhb + tt) * HS + dd] = __float2bfloat16((acc[mi][ni][r] + bv) * scale);
                }
            }
        } else {
            // V frag: transpose 128t x 16d through private scratch -> 16B stores
            int dbase = nb & 63;
            char* scr = smem + (w * 3 + ni) * 4096;   // 24 x 4KB = 96KB <= 112KB
#pragma unroll
            for (int mi = 0; mi < 8; ++mi) {
#pragma unroll
                for (int r = 0; r < 4; ++r) {
                    int m = mi * 16 + g * 4 + r;
                    __hip_bfloat16 hv = __float2bfloat16(acc[mi][ni][r] + bv);
                    *(ushort*)(scr + c * 256 + ((((m >> 3) ^ c) & 15) << 4) + (m & 7) * 2) = *(ushort*)&hv;
                }
            }
            size_t bh = (size_t)(b * NH + h);
#pragma unroll
            for (int p = 0; p < 4; ++p) {
                int d = p * 4 + g;
                bf16x8 vv = *(bf16x8*)(scr + d * 256 + (((c ^ d) & 15) << 4));
                *(bf16x8*)(&vto[(bh * HS + dbase + d) * T_SEQ + t0 + c * 8]) = vv;
            }
        }
    }
}

// ---------------- causal flash attention (R12 version, restored) ----------------
// 1024 blocks x 4 waves; one 64-row q-tile per block, big-tiles-first dispatch.
// LDS 40960B -> 4 independent blocks/CU. Single barrier/step; stage(t+1) issued
// AFTER barrier(t); depth-1 reg slack = one full compute step.
__launch_bounds__(256, 4)
__global__ void attn_fwd(const __hip_bfloat16* __restrict__ qb,   // [BH][T][64], *0.125*log2e
                         const __hip_bfloat16* __restrict__ kb,   // [BH][T][64]
                         const __hip_bfloat16* __restrict__ vtb,  // [BH][64][T]
                         float* __restrict__ out)                 // [B][T][C]
{
    // [0,16384): k_lds[2][64*64]  [16384,32768): v_lds[2][64*64]
    // [32768,40960): p strips, 2KB per wave, 128B rows, 16B-granule XOR swizzle
    __shared__ __align__(16) char smem[40960];

    int idx = blockIdx.x;
    int bh = idx & 31;
    int qt = 31 - (idx >> 5);            // big q-tiles dispatched first
    int w  = threadIdx.x >> 6;           // wave 0..3
    int lane = threadIdx.x & 63;
    int c = lane & 15, g = lane >> 4;
    char* p_strip = smem + 32768 + w * 2048;

    const __hip_bfloat16* Qp = qb  + (size_t)bh * T_SEQ * HS;
    const __hip_bfloat16* Kp = kb  + (size_t)bh * T_SEQ * HS;
    const __hip_bfloat16* Vp = vtb + (size_t)bh * HS * T_SEQ;
    int b = bh >> 4, h = bh & (NH - 1);

    int srow = lane >> 3;
    int scol = ((lane & 7) ^ srow) << 3;     // pre-swizzled source col (elems)
    int swz  = (c & 7) << 4;                 // K/V read-side XOR (bytes)
    int krow0 = w * 16 + srow;               // wave stages rows w*16..w*16+15
    int krow1 = w * 16 + 8 + srow;
    int qw = qt * 64 + w * 16;
    int ntile = qt + 1;

    bf16x8 qf[2];
    qf[0] = *(const bf16x8*)(&Qp[(size_t)(qw + c) * HS + g * 8]);
    qf[1] = *(const bf16x8*)(&Qp[(size_t)(qw + c) * HS + 32 + g * 8]);

    f32x4 oacc[4];
#pragma unroll
    for (int i = 0; i < 4; ++i) oacc[i] = (f32x4){0.f, 0.f, 0.f, 0.f};
    float lrow = 0.f;

#define ATT_STAGE(t_, buf_) { \
    int k0_ = (t_) * 64; \
    char* kb_ = smem + (buf_) * 8192; \
    char* vb_ = smem + 16384 + (buf_) * 8192; \
    gld_lds16(&Kp[(size_t)(k0_ + krow0) * HS + scol],  kb_ + (w * 16) * 128); \
    gld_lds16(&Kp[(size_t)(k0_ + krow1) * HS + scol],  kb_ + (w * 16 + 8) * 128); \
    gld_lds16(&Vp[(size_t)krow0 * T_SEQ + k0_ + scol], vb_ + (w * 16) * 128); \
    gld_lds16(&Vp[(size_t)krow1 * T_SEQ + k0_ + scol], vb_ + (w * 16 + 8) * 128); }

    // prologue: stage tile 0 into buf 0
    ATT_STAGE(0, 0);

    for (int tix = 0; tix < ntile; ++tix) {
        int cur = tix & 1;
        asm volatile("s_waitcnt vmcnt(0)" ::: "memory");   // own stage(tix) loads landed
        __builtin_amdgcn_s_barrier();                      // all waves' stages landed
        if (tix + 1 < ntile) ATT_STAGE(tix + 1, cur ^ 1);  // safe: after barrier

        bool diag = (tix == ntile - 1);
        const char* KL = smem + cur * 8192;
        const char* VL = smem + 16384 + cur * 8192;

        // ---- S^T = K Q^T: sacc[kc] lane (c,g): P[q=c][k=kc*16+g*4+r] ----
        f32x4 sacc[4];
#pragma unroll
        for (int i = 0; i < 4; ++i) sacc[i] = (f32x4){0.f, 0.f, 0.f, 0.f};
        __builtin_amdgcn_s_setprio(1);
#pragma unroll
        for (int ks = 0; ks < 2; ++ks)
#pragma unroll
            for (int kc = 0; kc < 4; ++kc)
                if (!diag || kc <= w) {
                    int rr = kc * 16 + c;
                    int colB = (ks * 64 + g * 16) ^ swz;
                    bf16x8 kf = *(const bf16x8*)(KL + rr * 128 + colB);
                    sacc[kc] = __builtin_amdgcn_mfma_f32_16x16x32_bf16(kf, qf[ks], sacc[kc], 0, 0, 0);
                }
        __builtin_amdgcn_s_setprio(0);

        // ---- P = exp2(S), lane-local sum, pack pairs, swizzled 8B writes ----
#pragma unroll
        for (int kc = 0; kc < 4; ++kc) {
            float p0, p1, p2, p3;
            if (!diag) {
                p0 = __builtin_amdgcn_exp2f(sacc[kc][0]);
                p1 = __builtin_amdgcn_exp2f(sacc[kc][1]);
                p2 = __builtin_amdgcn_exp2f(sacc[kc][2]);
                p3 = __builtin_amdgcn_exp2f(sacc[kc][3]);
            } else {
                int kbase = kc * 16 + g * 4;
                int lim = w * 16 + c;
                p0 = (kc <= w && kbase + 0 <= lim) ? __builtin_amdgcn_exp2f(sacc[kc][0]) : 0.f;
                p1 = (kc <= w && kbase + 1 <= lim) ? __builtin_amdgcn_exp2f(sacc[kc][1]) : 0.f;
                p2 = (kc <= w && kbase + 2 <= lim) ? __builtin_amdgcn_exp2f(sacc[kc][2]) : 0.f;
                p3 = (kc <= w && kbase + 3 <= lim) ? __builtin_amdgcn_exp2f(sacc[kc][3]) : 0.f;
            }
            lrow += (p0 + p1) + (p2 + p3);
            unsigned lo = ((__builtin_bit_cast(unsigned, p0) + 0x8000u) >> 16) |
                          ((__builtin_bit_cast(unsigned, p1) + 0x8000u) & 0xffff0000u);
            unsigned hi = ((__builtin_bit_cast(unsigned, p2) + 0x8000u) >> 16) |
                          ((__builtin_bit_cast(unsigned, p3) + 0x8000u) & 0xffff0000u);
            // logical granule kc*2 + (g>>1), XOR (c&7); low/high 8B by g&1
            int gran = ((kc * 2 + (g >> 1)) ^ (c & 7)) << 4;
            *(uint2*)(p_strip + c * 128 + gran + ((g & 1) << 3)) = make_uint2(lo, hi);
        }

        // ---- O^T += V^T P^T ----
        int ksm = diag ? ((w >= 2) ? 2 : 1) : 2;
        __builtin_amdgcn_s_setprio(1);
#pragma unroll
        for (int ks = 0; ks < 2; ++ks) {
            if (ks >= ksm) break;
            int pgran = ((ks * 4 + g) ^ (c & 7)) << 4;
            bf16x8 pf = *(bf16x8*)(p_strip + c * 128 + pgran);
#pragma unroll
            for (int d16 = 0; d16 < 4; ++d16) {
                int dr = d16 * 16 + c;
                int colB = (ks * 64 + g * 16) ^ swz;
                bf16x8 vf = *(const bf16x8*)(VL + dr * 128 + colB);
                oacc[d16] = __builtin_amdgcn_mfma_f32_16x16x32_bf16(vf, pf, oacc[d16], 0, 0, 0);
            }
        }
        __builtin_amdgcn_s_setprio(0);
    }

    // ---- finalize: 2 shuffles, normalize, float4 stores ----
    float v = lrow;
    v += __shfl_xor(v, 16, 64);
    v += __shfl_xor(v, 32, 64);
    float linv = 1.0f / v;
    float* orow = &out[((size_t)(b * T_SEQ + qw + c)) * C_EMB + h * HS + g * 4];
#pragma unroll
    for (int d16 = 0; d16 < 4; ++d16) {
        float4 st;
        st.x = oacc[d16][0] * linv;
        st.y = oacc[d16][1] * linv;
        st.z = oacc[d16][2] * linv;
        st.w = oacc[d16][3] * linv;
        *(float4*)(&orow[d16 * 16]) = st;
    }
#undef ATT_STAGE
}

// ---------------- launch ----------------
extern "C" void kernel_launch(void* const* d_in, const int* in_sizes, int n_in,
                              void* d_out, int out_size, void* d_ws, size_t ws_size,
                              hipStream_t stream) {
    const float* x    = (const float*)d_in[0];   // [2][2048][1024]
    const float* W    = (const float*)d_in[1];   // [3072][1024]
    const float* bias = (const float*)d_in[2];   // [3072]
    float* out = (float*)d_out;

    char* ws = (char*)d_ws;
    __hip_bfloat16* xb  = (__hip_bfloat16*)(ws);                      // 8 MB
    __hip_bfloat16* wb  = (__hip_bfloat16*)(ws + (8u  << 20));        // 6 MB
    __hip_bfloat16* qo  = (__hip_bfloat16*)(ws + (14u << 20));        // 8 MB
    __hip_bfloat16* ko  = (__hip_bfloat16*)(ws + (22u << 20));        // 8 MB
    __hip_bfloat16* vto = (__hip_bfloat16*)(ws + (30u << 20));        // 8 MB

    int n4x = BATCH * T_SEQ * C_EMB / 4;      // 1048576
    int n4w = 3 * C_EMB * C_EMB / 4;          // 786432
    int n4  = n4x + n4w;
    cvt_f32_bf16<<<(n4 + 255) / 256, 256, 0, stream>>>(
        (const float4*)x, (ushort4*)xb, n4x,
        (const float4*)W, (ushort4*)wb, n4w);

    int gemm_grid = (BATCH * T_SEQ / 256) * (3 * C_EMB / 192);  // 16*16 = 256
    qkv_gemm<<<gemm_grid, 512, 0, stream>>>(xb, wb, bias, qo, ko, vto);

    attn_fwd<<<1024, 256, 0, stream>>>(qo, ko, vto, out);
}